// Round 8
// baseline (291.474 us; speedup 1.0000x reference)
//
#include <hip/hip_runtime.h>
#include <stdint.h>

typedef _Float16 f16;
typedef f16 half2_t __attribute__((ext_vector_type(2)));
typedef f16 half4_t __attribute__((ext_vector_type(4)));
typedef f16 half8_t __attribute__((ext_vector_type(8)));
typedef __fp16 fp16x2_t __attribute__((ext_vector_type(2)));
typedef float f32x4 __attribute__((ext_vector_type(4)));
typedef float f32x16 __attribute__((ext_vector_type(16)));
typedef int int4_t __attribute__((ext_vector_type(4)));

#define N_ 4
#define S_ 2048
#define D_ 1024
#define H_ 16
#define HD_ 64
#define LOG2E 1.44269504088896340736f
#define SCALE_ 0.03125f   /* 1/sqrt(1024) */

typedef __attribute__((address_space(1))) void gvoid;
typedef __attribute__((address_space(3))) void lvoid;

__device__ __forceinline__ void load_lds16(const void* g, void* l) {
  __builtin_amdgcn_global_load_lds((gvoid*)(uintptr_t)g, (lvoid*)l, 16, 0, 0);
}

__device__ __forceinline__ f32x16 mfma3216(half8_t a, half8_t b, f32x16 c) {
  return __builtin_amdgcn_mfma_f32_32x32x16_f16(a, b, c, 0, 0, 0);
}
__device__ __forceinline__ f32x4 mfma1632(half8_t a, half8_t b, f32x4 c) {
  return __builtin_amdgcn_mfma_f32_16x16x32_f16(a, b, c, 0, 0, 0);
}

__device__ __forceinline__ int pack_f16i(float a, float b) {
  fp16x2_t t = __builtin_amdgcn_cvt_pkrtz(a, b);
  return __builtin_bit_cast(int, t);
}

// ---------------- weight prep (Wbig + Mq) ----------------
__global__ void wprep(const float* __restrict__ Wv, const float* __restrict__ Wo,
                      const float* __restrict__ Wq, const float* __restrict__ Wk,
                      f16* __restrict__ Wbig, float* __restrict__ Mq) {
  int b = blockIdx.x;
  if (b < 1024) {
    int j = b;
#pragma unroll
    for (int c = 0; c < 4; ++c) {
      int i = c * 256 + threadIdx.x;
      int h = i >> 6, dd = i & 63;
      const float* wo = Wo + (size_t)j * 1024 + h * 64;
      float acc = 0.f;
#pragma unroll 8
      for (int e = 0; e < 64; ++e) acc += Wv[e * 64 + dd] * wo[e];
      Wbig[(size_t)j * 1024 + i] = (f16)acc;
    }
  } else {
    int tid = (b - 1024) * 256 + threadIdx.x;  // 4096 threads
    int d = tid >> 6, e = tid & 63;
    float acc = 0.f;
#pragma unroll 8
    for (int r = 0; r < 64; ++r) acc += Wq[r * 64 + d] * Wk[r * 64 + e];
    Mq[d * 64 + e] = acc * (SCALE_ * LOG2E);
  }
}

// ---------------- prep2 — 32x32-fragment-native layouts ----------------
// q16/k16: per nh: 64 s-chunks(32 rows) x 4 d-chunks(16): chunk=((nh*64+sc)*4+dc),
//   1KB: slot(g8*32+m) holds X[s=sc*32+m][d=dc*16+g8*8+j] j=0..7  (32x32x16 A/B frag)
// v16: per nh: 128 s-chunks(16) x 2 d-chunks(32): chunk=((nh*128+sc16)*2+dc32),
//   slot(g8*32+m) holds V[s=sc16*16+g8*8+j][d=dc32*32+m]          (32x32x16 A frag)
__global__ __launch_bounds__(256) void prep2(const float* __restrict__ Q,
                                             const float* __restrict__ K,
                                             const float* __restrict__ V,
                                             const float* __restrict__ Mq,
                                             f16* __restrict__ q16, f16* __restrict__ k16,
                                             f16* __restrict__ v16) {
  __shared__ float mql[64 * 64];
  int b = blockIdx.x;
  if (b < 512) {
#pragma unroll
    for (int c = 0; c < 16; ++c) mql[c * 256 + threadIdx.x] = Mq[c * 256 + threadIdx.x];
    __syncthreads();
    int n = b >> 7, sblk = b & 127;  // 16-row s-blocks
    int L = threadIdx.x & 63, w = threadIdx.x >> 6;
    int lq = L & 15, hh = w * 4 + (L >> 4);
    int s = sblk * 16 + lq;
    const float* qrow = Q + ((size_t)(n * S_ + s)) * D_ + hh * HD_;
    f32x4 acc4[16];
#pragma unroll
    for (int i = 0; i < 16; ++i) acc4[i] = (f32x4){0.f, 0.f, 0.f, 0.f};
    for (int d4 = 0; d4 < 16; ++d4) {
      f32x4 qv = *(const f32x4*)(qrow + d4 * 4);
#pragma unroll
      for (int dj = 0; dj < 4; ++dj) {
        const f32x4* mrow = (const f32x4*)(mql + (d4 * 4 + dj) * 64);  // broadcast
        float qs = qv[dj];
#pragma unroll
        for (int i = 0; i < 16; ++i) acc4[i] += mrow[i] * qs;
      }
    }
    int nh = n * 16 + hh, sc = sblk >> 1;
    int sh = (sblk & 1) * 16 + lq;  // s % 32
#pragma unroll
    for (int dc = 0; dc < 4; ++dc) {
#pragma unroll
      for (int g8 = 0; g8 < 2; ++g8) {
        int i0 = dc * 4 + g8 * 2;
        half8_t hv;
#pragma unroll
        for (int j = 0; j < 4; ++j) { hv[j] = (f16)acc4[i0][j]; hv[4 + j] = (f16)acc4[i0 + 1][j]; }
        *(half8_t*)(q16 + ((size_t)((nh * 64 + sc) * 4 + dc)) * 512 + (g8 * 32 + sh) * 8) = hv;
      }
    }
    const float* krow = K + ((size_t)(n * S_ + s)) * D_ + hh * HD_;
    f32x4 kr[16];
#pragma unroll
    for (int i = 0; i < 16; ++i) kr[i] = *(const f32x4*)(krow + i * 4);
#pragma unroll
    for (int dc = 0; dc < 4; ++dc) {
#pragma unroll
      for (int g8 = 0; g8 < 2; ++g8) {
        int i0 = dc * 4 + g8 * 2;
        half8_t hv;
#pragma unroll
        for (int j = 0; j < 4; ++j) { hv[j] = (f16)kr[i0][j]; hv[4 + j] = (f16)kr[i0 + 1][j]; }
        *(half8_t*)(k16 + ((size_t)((nh * 64 + sc) * 4 + dc)) * 512 + (g8 * 32 + sh) * 8) = hv;
      }
    }
  } else {
    // V: direct coalesced gather (8 rows x 1 col per lane), no LDS
    int t = threadIdx.x;
    int ci = (b - 512) * 4 + (t >> 6);       // global chunk 0..16383
    int slot = t & 63;
    int dc32 = ci & 1, sc16 = (ci >> 1) & 127, nh = ci >> 8;
    int n = nh >> 4, hh = nh & 15;
    int g8 = slot >> 5, m = slot & 31;
    int dglob = hh * 64 + dc32 * 32 + m;
    int sbase = sc16 * 16 + g8 * 8;
    const float* src = V + ((size_t)(n * S_ + sbase)) * D_ + dglob;
    half8_t hv;
#pragma unroll
    for (int j = 0; j < 8; ++j) hv[j] = (f16)src[(size_t)j * D_];
    *(half8_t*)(v16 + (size_t)ci * 512 + slot * 8) = hv;
  }
}

// ---------------- flash: 32x32 MFMA datapath, K+V dbuf, 1 barrier/iter ----------
// grid (x=nh 64, y=qt2 16) -> XCD = nh%8. Wave w owns q-chunk qt2*4+w (32 q).
// phase1 C-layout -> phase2 B-operand via shfl_xor(32) + cndmask (per 32-s chunk).
__global__ __launch_bounds__(256, 2) void flash(const f16* __restrict__ q16,
                                                const f16* __restrict__ k16,
                                                const f16* __restrict__ v16,
                                                f16* __restrict__ att) {
  __shared__ char lds[65536];  // K dbuf 0/16K, V dbuf 32K/48K
  int nh = blockIdx.x;
  int qt2 = blockIdx.y;
  int L = threadIdx.x & 63, w = threadIdx.x >> 6;
  int g8 = L >> 5;
  bool hi = g8 != 0;

  // q'' B-fragments (32 q x 64 d), direct from global
  const f16* qptr = q16 + ((size_t)((nh * 64 + qt2 * 4 + w) * 4)) * 512 + L * 8;
  half8_t qB[4];
#pragma unroll
  for (int dc = 0; dc < 4; ++dc) qB[dc] = *(const half8_t*)(qptr + dc * 512);

  f32x16 acc0 = {0.f,0.f,0.f,0.f,0.f,0.f,0.f,0.f,0.f,0.f,0.f,0.f,0.f,0.f,0.f,0.f};
  f32x16 acc1 = acc0;
  f32x4 lvec = (f32x4){0.f, 0.f, 0.f, 0.f};

  const char* kg = (const char*)k16 + (size_t)nh * 262144 + w * 4096 + L * 16;
  const char* vg = (const char*)v16 + (size_t)nh * 262144 + w * 4096 + L * 16;

  // prologue: tiles 0 and 1 into both buffers
#pragma unroll
  for (int tt = 0; tt < 2; ++tt)
#pragma unroll
    for (int c = 0; c < 4; ++c) {
      load_lds16(kg + tt * 16384 + c * 1024, lds + tt * 16384 + w * 4096 + c * 1024);
      load_lds16(vg + tt * 16384 + c * 1024, lds + 32768 + tt * 16384 + w * 4096 + c * 1024);
    }
  __syncthreads();

  for (int it = 0; it < 16; ++it) {
    const char* kb = lds + (it & 1) * 16384;
    const char* vb = lds + 32768 + (it & 1) * 16384;
#pragma unroll
    for (int c = 0; c < 4; ++c) {  // 32-s chunk
      // phase1: S^T[32 s][32 q], K-dim 64 = 4 x K16
      f32x16 aS = {0.f,0.f,0.f,0.f,0.f,0.f,0.f,0.f,0.f,0.f,0.f,0.f,0.f,0.f,0.f,0.f};
#pragma unroll
      for (int dc = 0; dc < 4; ++dc) {
        half8_t kf = *(const half8_t*)(kb + (c * 4 + dc) * 1024 + L * 16);
        aS = mfma3216(kf, qB[dc], aS);
      }
      // softmax: p = exp2(s) (scale folded); row-sum into lvec (col=q fixed/lane)
      f32x4 pv[4];
#pragma unroll
      for (int r4 = 0; r4 < 4; ++r4) {
#pragma unroll
        for (int e = 0; e < 4; ++e) pv[r4][e] = __builtin_amdgcn_exp2f(aS[r4 * 4 + e]);
        lvec += pv[r4];
      }
      int pk[8];
#pragma unroll
      for (int i = 0; i < 8; ++i)
        pk[i] = pack_f16i(pv[i >> 1][(i & 1) * 2], pv[i >> 1][(i & 1) * 2 + 1]);
      int sw[8];
#pragma unroll
      for (int i = 0; i < 8; ++i) sw[i] = __shfl_xor(pk[i], 32, 64);
      // assemble P^T B-frags for the two 16-s halves of this chunk
      half8_t fr[2];
#pragma unroll
      for (int sc2 = 0; sc2 < 2; ++sc2) {
        int ba = sc2 * 4;
        int4_t iv;
        iv[0] = hi ? sw[ba + 2] : pk[ba + 0];
        iv[1] = hi ? sw[ba + 3] : pk[ba + 1];
        iv[2] = hi ? pk[ba + 2] : sw[ba + 0];
        iv[3] = hi ? pk[ba + 3] : sw[ba + 1];
        fr[sc2] = __builtin_bit_cast(half8_t, iv);
      }
      // phase2: O^T[64 d][32 q] += V^T x P^T  (4 x 32x32x16)
#pragma unroll
      for (int sc2 = 0; sc2 < 2; ++sc2) {
        half8_t vf0 = *(const half8_t*)(vb + ((c * 2 + sc2) * 2 + 0) * 1024 + L * 16);
        acc0 = mfma3216(vf0, fr[sc2], acc0);
        half8_t vf1 = *(const half8_t*)(vb + ((c * 2 + sc2) * 2 + 1) * 1024 + L * 16);
        acc1 = mfma3216(vf1, fr[sc2], acc1);
      }
    }
    __syncthreads();  // readers of buf[it&1] done; drains tiles(it+1) in flight
    if (it + 2 < 16) {
      char* dk = lds + (it & 1) * 16384 + w * 4096;
      char* dv = lds + 32768 + (it & 1) * 16384 + w * 4096;
#pragma unroll
      for (int c = 0; c < 4; ++c) {
        load_lds16(kg + (size_t)(it + 2) * 16384 + c * 1024, dk + c * 1024);
        load_lds16(vg + (size_t)(it + 2) * 16384 + c * 1024, dv + c * 1024);
      }
    }
  }

  // epilogue: l per q-col lives in this lane and its ^32 partner
  float l = lvec[0] + lvec[1] + lvec[2] + lvec[3];
  l += __shfl_xor(l, 32, 64);
  float inv = 1.0f / l;
  int n = nh >> 4, h = nh & 15;
  int s = (qt2 * 4 + w) * 32 + (L & 31);
  f16* base = att + ((size_t)(n * S_ + s)) * D_ + h * HD_;
#pragma unroll
  for (int dt = 0; dt < 2; ++dt) {
    f32x16 A = dt ? acc1 : acc0;
#pragma unroll
    for (int blk = 0; blk < 4; ++blk) {
      half4_t o;
#pragma unroll
      for (int r = 0; r < 4; ++r) o[r] = (f16)(A[blk * 4 + r] * inv);
      *(half4_t*)(base + dt * 32 + blk * 8 + g8 * 4) = o;
    }
  }
}

// ---------------- output GEMM: XOR-swizzled LDS, double-buffer, 1 barrier/iter ----
__global__ __launch_bounds__(256, 2) void ogemm(const f16* __restrict__ A, const f16* __restrict__ Bm,
                                                const float* __restrict__ bias, float* __restrict__ C) {
  __shared__ char lds[32768];  // buf[2] x (A 8K + B 8K)
  int bm = blockIdx.x, bn = blockIdx.y;
  int L = threadIdx.x & 63, w = threadIdx.x >> 6;
  int wm = w >> 1, wn = w & 1;
  int lq = L & 15, quad = L >> 4;
  int lr = L >> 2, lc = L & 3;
  int src_c = lc ^ (lr & 3);
  f32x4 acc[16];
#pragma unroll
  for (int i = 0; i < 16; ++i) acc[i] = (f32x4){0.f, 0.f, 0.f, 0.f};

  const f16* ga0 = A + ((size_t)(bm * 128 + (w * 2) * 16 + lr)) * 1024 + src_c * 8;
  const f16* gb0 = Bm + ((size_t)(bn * 128 + (w * 2) * 16 + lr)) * 1024 + src_c * 8;

#pragma unroll
  for (int t = 0; t < 2; ++t)
#pragma unroll
    for (int c = 0; c < 2; ++c) {
      load_lds16(ga0 + t * 32 + (size_t)c * 16 * 1024, lds + t * 16384 + (w * 2 + c) * 1024);
      load_lds16(gb0 + t * 32 + (size_t)c * 16 * 1024, lds + t * 16384 + 8192 + (w * 2 + c) * 1024);
    }
  __syncthreads();

  for (int kt = 0; kt < 32; ++kt) {
    const char* base = lds + (kt & 1) * 16384;
    half8_t af[4], bf[4];
#pragma unroll
    for (int t = 0; t < 4; ++t) {
      int ch = quad ^ (lq & 3);
      af[t] = *(const half8_t*)(base + (wm * 64 + t * 16 + lq) * 64 + ch * 16);
      bf[t] = *(const half8_t*)(base + 8192 + (wn * 64 + t * 16 + lq) * 64 + ch * 16);
    }
#pragma unroll
    for (int mt = 0; mt < 4; ++mt)
#pragma unroll
      for (int nt = 0; nt < 4; ++nt)
        acc[mt * 4 + nt] = mfma1632(af[mt], bf[nt], acc[mt * 4 + nt]);
    __syncthreads();
    if (kt + 2 < 32) {
      char* dst = lds + (kt & 1) * 16384;
#pragma unroll
      for (int c = 0; c < 2; ++c) {
        load_lds16(ga0 + (kt + 2) * 32 + (size_t)c * 16 * 1024, dst + (w * 2 + c) * 1024);
        load_lds16(gb0 + (kt + 2) * 32 + (size_t)c * 16 * 1024, dst + 8192 + (w * 2 + c) * 1024);
      }
    }
  }

#pragma unroll
  for (int nt = 0; nt < 4; ++nt) {
    int col = bn * 128 + wn * 64 + nt * 16 + lq;
    float bv = bias[col];
#pragma unroll
    for (int mt = 0; mt < 4; ++mt) {
#pragma unroll
      for (int r = 0; r < 4; ++r) {
        int row = bm * 128 + wm * 64 + mt * 16 + quad * 4 + r;
        C[(size_t)row * 1024 + col] = acc[mt * 4 + nt][r] + bv;
      }
    }
  }
}

extern "C" void kernel_launch(void* const* d_in, const int* in_sizes, int n_in,
                              void* d_out, int out_size, void* d_ws, size_t ws_size,
                              hipStream_t stream) {
  const float* V  = (const float*)d_in[0];
  const float* K  = (const float*)d_in[1];
  const float* Q  = (const float*)d_in[2];
  const float* Wv = (const float*)d_in[3];
  const float* Wk = (const float*)d_in[4];
  const float* Wq = (const float*)d_in[5];
  const float* Wo = (const float*)d_in[6];
  const float* bo = (const float*)d_in[7];
  float* out = (float*)d_out;

  char* ws = (char*)d_ws;
  float* Mq  = (float*)(ws);                          // 16 KB
  f16* Wbig  = (f16*)(ws + (1ull << 20));             // 2 MB
  f16* q16   = (f16*)(ws + (3ull << 20));             // 16 MB
  f16* k16   = (f16*)(ws + (19ull << 20));            // 16 MB
  f16* v16   = (f16*)(ws + (35ull << 20));            // 16 MB
  f16* att   = (f16*)(ws + (51ull << 20));            // 16 MB -> total 67 MB

  wprep<<<1040, 256, 0, stream>>>(Wv, Wo, Wq, Wk, Wbig, Mq);
  prep2<<<4608, 256, 0, stream>>>(Q, K, V, Mq, q16, k16, v16);
  flash<<<dim3(64, 16), 256, 0, stream>>>(q16, k16, v16, att);
  ogemm<<<dim3(64, 8), 256, 0, stream>>>(att, Wbig, bo, out);
}